// Round 1
// baseline (345.447 us; speedup 1.0000x reference)
//
#include <hip/hip_runtime.h>
#include <math.h>

#define B_SZ 128
#define D_SZ 128

typedef __attribute__((ext_vector_type(8))) short bf16x8;
typedef __attribute__((ext_vector_type(4))) float f32x4;

__device__ __forceinline__ unsigned short f2bf(float f) {
    unsigned u = __float_as_uint(f);
    unsigned r = (u + 0x7FFF + ((u >> 16) & 1)) >> 16;   // RNE; inputs finite
    return (unsigned short)r;
}

// fast tanh: 1 - 2/(e^{2x}+1) via v_exp_f32 + v_rcp_f32 (~1e-6 abs err,
// well under the bf16 truncation applied right after).
__device__ __forceinline__ float fast_tanh(float x) {
    float e2 = __builtin_amdgcn_exp2f(x * 2.885390081777927f);  // 2*log2(e)
    return fmaf(-2.0f, __builtin_amdgcn_rcpf(e2 + 1.0f), 1.0f);
}

// ---------------------------------------------------------------------------
// castT_tile: one 64(n) x 128(c) tile of fp32 (B,L,128) -> bf16 (B,128,L).
// ---------------------------------------------------------------------------
__device__ __forceinline__ void castT_tile(
    const float* __restrict__ src, unsigned short* __restrict__ dst,
    int b, int n0, int L)
{
    __shared__ unsigned short tt[128][72];
    const int tid = threadIdx.x;
    for (int i = tid; i < 64 * 32; i += 256) {
        int nr = i >> 5, c4 = (i & 31) * 4;
        float4 v = *(const float4*)(src + ((size_t)b * L + n0 + nr) * 128 + c4);
        tt[c4 + 0][nr] = f2bf(v.x);
        tt[c4 + 1][nr] = f2bf(v.y);
        tt[c4 + 2][nr] = f2bf(v.z);
        tt[c4 + 3][nr] = f2bf(v.w);
    }
    __syncthreads();
    const int c = tid >> 1, seg = (tid & 1) * 32;
    unsigned short* dp = dst + ((size_t)b * 128 + c) * L + n0 + seg;
    #pragma unroll
    for (int j = 0; j < 32; j += 8)
        *(bf16x8*)(dp + j) = *(const bf16x8*)&tt[c][seg + j];
}

// ---------------------------------------------------------------------------
// prep_all: ONE dispatch for all independent prep work.
// ---------------------------------------------------------------------------
__global__ __launch_bounds__(256) void prep_all(
    const float* __restrict__ x1, const float* __restrict__ x2,
    const float* __restrict__ x3,
    unsigned short* __restrict__ Xt1, unsigned short* __restrict__ Xt2,
    unsigned short* __restrict__ Xt3,
    unsigned short* __restrict__ U256, unsigned short* __restrict__ U128,
    unsigned short* __restrict__ U64p,
    const float* __restrict__ c0, const float* __restrict__ c1,
    const float* __restrict__ c2, const float* __restrict__ c3,
    unsigned short* __restrict__ BmT_all, float* __restrict__ bias_all)
{
    const int bid = blockIdx.x, tid = threadIdx.x;
    if (bid < 896) {
        if (bid < 512)      castT_tile(x1, Xt1, bid >> 2, (bid & 3) * 64, 256);
        else if (bid < 768) castT_tile(x2, Xt2, (bid - 512) >> 1, ((bid - 512) & 1) * 64, 128);
        else                castT_tile(x3, Xt3, bid - 768, 0, 64);
    } else if (bid < 1568) {
        // U[2t,n] = (t==n)*0.25 + (-1)^{t+n}/4L ; U[2t+1,n] = s((t-n)%L)/4L
        int fid = (bid - 896) * 256 + tid;
        unsigned short* U; int L, lg, e;
        if (fid < 131072)      { U = U256; L = 256; lg = 8; e = fid; }
        else if (fid < 163840) { U = U128; L = 128; lg = 7; e = fid - 131072; }
        else                   { U = U64p; L = 64;  lg = 6; e = fid - 163840; }
        const int n = e & (L - 1);
        const int m = e >> lg;
        const int t = m >> 1;
        const float inv4L = 1.0f / (4.0f * (float)L);
        float val;
        if ((m & 1) == 0) {
            val = ((t == n) ? 0.25f : 0.0f) + (((t + n) & 1) ? -inv4L : inv4L);
        } else {
            int idx = (t - n) & (L - 1);
            double th = M_PI * (2.0 * idx + 1.0) / (2.0 * L);
            double ct = cos(th) / sin(th);
            val = (float)((idx & 1) ? -ct : ct) * inv4L;
        }
        U[e] = f2bf(val);
    } else {
        // convb: BmT[set][d-1][o][i] = bf16(coeffs[i,o,d]); bias = sum_i c[i,o,0]
        const int r   = bid - 1568;          // 0..255
        const int set = r >> 6;              // 0..3  (DEG1 = set+2)
        const int o   = ((r & 63) << 1) + (tid >> 7);
        const int i   = tid & 127;
        const int DEG1 = set + 2;
        const float* cc = (set == 0) ? c0 : (set == 1) ? c1 : (set == 2) ? c2 : c3;
        const float* cp = cc + ((size_t)i * 128 + o) * DEG1;
        unsigned short* Bm = BmT_all + (size_t)set * 65536;
        for (int d = 1; d < DEG1; ++d)
            Bm[(size_t)(d - 1) * 16384 + o * 128 + i] = f2bf(cp[d]);
        float s = cp[0];
        #pragma unroll
        for (int off = 32; off >= 1; off >>= 1) s += __shfl_down(s, off);
        __shared__ float red[4];
        if ((tid & 63) == 0) red[tid >> 6] = s;
        __syncthreads();
        if ((tid & 127) == 0)
            bias_all[set * 128 + o] = red[tid >> 6] + red[(tid >> 6) + 1];
    }
}

// ---------------------------------------------------------------------------
// up2_body: out[b,m,c] = xh[b,m,c] + sign * sum_n U[m,n]*Xt[b,c,n]
// 64x128 tile, 4 waves 2x2 of 32x64, mfma 16x16x32 bf16, runtime L.
// R5: barrier-free register GEMM — U (<=256KB, level-shared) and Xt[b]
// panels are L2-resident, so A/B fragments are loaded DIRECT from global
// (coalesced 64B rows) with a 1-deep register prefetch. No LDS, no
// __syncthreads, no staging VALU.
// ---------------------------------------------------------------------------
__device__ __forceinline__ void up2_body(
    const unsigned short* __restrict__ U,
    const unsigned short* __restrict__ Xt,
    const float* __restrict__ xh,
    float* __restrict__ out,
    unsigned short* __restrict__ xtm,
    float sign, int b, int mt, int L)
{
    const int NK = L >> 5;
    const int tid = threadIdx.x;
    const int ln = tid & 63, wv = tid >> 6;
    const int wm = wv & 1, wn = wv >> 1;
    const int lr = ln & 15, qd = ln >> 4;

    f32x4 acc[2][4];
    #pragma unroll
    for (int mi = 0; mi < 2; ++mi)
        #pragma unroll
        for (int nt = 0; nt < 4; ++nt)
            acc[mi][nt] = (f32x4){0.f, 0.f, 0.f, 0.f};

    // per-lane fragment base pointers (fragment indices identical to the
    // previous LDS-staged version — just read at the global source).
    const unsigned short* Ap = U + (size_t)(mt * 64 + wm * 32 + lr) * L + (qd << 3);
    const unsigned short* Bp = Xt + ((size_t)b * 128 + (wn << 6) + lr) * L + (qd << 3);
    const int aStride = L << 4;   // 16 rows (shorts)
    const int bStride = L << 4;

    bf16x8 ac[2], bc[4], an[2], bn[4];
    #pragma unroll
    for (int mi = 0; mi < 2; ++mi) ac[mi] = *(const bf16x8*)(Ap + mi * aStride);
    #pragma unroll
    for (int nt = 0; nt < 4; ++nt) bc[nt] = *(const bf16x8*)(Bp + nt * bStride);

    for (int kk = 0; kk < NK; ++kk) {
        const bool pf = (kk + 1 < NK);
        if (pf) {
            const int ko = (kk + 1) << 5;
            #pragma unroll
            for (int mi = 0; mi < 2; ++mi)
                an[mi] = *(const bf16x8*)(Ap + mi * aStride + ko);
            #pragma unroll
            for (int nt = 0; nt < 4; ++nt)
                bn[nt] = *(const bf16x8*)(Bp + nt * bStride + ko);
        }
        #pragma unroll
        for (int mi = 0; mi < 2; ++mi)
            #pragma unroll
            for (int nt = 0; nt < 4; ++nt)
                acc[mi][nt] = __builtin_amdgcn_mfma_f32_16x16x32_bf16(
                    ac[mi], bc[nt], acc[mi][nt], 0, 0, 0);
        if (pf) {
            #pragma unroll
            for (int mi = 0; mi < 2; ++mi) ac[mi] = an[mi];
            #pragma unroll
            for (int nt = 0; nt < 4; ++nt) bc[nt] = bn[nt];
        }
    }

    const int twoL = L << 1;
    #pragma unroll
    for (int nt = 0; nt < 4; ++nt) {
        const int col = wn * 64 + nt * 16 + lr;
        #pragma unroll
        for (int mi = 0; mi < 2; ++mi) {
            #pragma unroll
            for (int r = 0; r < 4; ++r) {
                const int row = mt * 64 + wm * 32 + mi * 16 + qd * 4 + r;
                const size_t gi = ((size_t)b * twoL + row) * 128 + col;
                float v = xh[gi] + sign * acc[mi][nt][r];
                out[gi] = v;
                if (xtm)
                    xtm[((size_t)b * 128 + col) * twoL + row] = f2bf(v);
            }
        }
    }
}

// up2_dec: all three decomposition GEMMs in ONE dispatch.
__global__ __launch_bounds__(256) void up2_dec(
    const unsigned short* __restrict__ U64p, const unsigned short* __restrict__ U128,
    const unsigned short* __restrict__ U256,
    const unsigned short* __restrict__ Xt3, const unsigned short* __restrict__ Xt2,
    const unsigned short* __restrict__ Xt1,
    const float* __restrict__ x2, const float* __restrict__ x1,
    const float* __restrict__ x0,
    float* __restrict__ d2, float* __restrict__ d1, float* __restrict__ d0)
{
    const int bid = blockIdx.x;
    const unsigned short *U, *Xt; const float* xh; float* out;
    int L, lgMT, base;
    if (bid < 256)      { U = U64p; Xt = Xt3; xh = x2; out = d2; L = 64;  lgMT = 1; base = 0; }
    else if (bid < 768) { U = U128; Xt = Xt2; xh = x1; out = d1; L = 128; lgMT = 2; base = 256; }
    else                { U = U256; Xt = Xt1; xh = x0; out = d0; L = 256; lgMT = 3; base = 768; }
    const int rb = bid - base;
    up2_body(U, Xt, xh, out, nullptr, -1.f, rb >> lgMT, rb & ((1 << lgMT) - 1), L);
}

// up2_mix: one mix-chain up-add (in-place), optional Xtm emit for next level.
__global__ __launch_bounds__(256) void up2_mix(
    const unsigned short* __restrict__ U, const unsigned short* __restrict__ Xt,
    float* __restrict__ m, unsigned short* __restrict__ xtm, int L, int lgMT)
{
    up2_body(U, Xt, m, m, xtm, 1.f,
             blockIdx.x >> lgMT, blockIdx.x & ((1 << lgMT) - 1), L);
}

// ---------------------------------------------------------------------------
// mkan_all: ALL FOUR mkan levels in one dispatch, prep_T fused in-LDS.
// R5: Bb LDS staging removed — BmT (<=128KB/level, shared by every block of
// the level) is L2-resident, so B fragments load DIRECT from global with a
// 1-deep register prefetch. ONE __syncthreads total (after As prep).
// LDS = As 32KB only -> 5 blocks/CU. tanh via fast exp2/rcp.
// ---------------------------------------------------------------------------
__global__ __launch_bounds__(256) void mkan_all(
    const float* __restrict__ xa, const float* __restrict__ xb,
    const float* __restrict__ xc, const float* __restrict__ xd,
    const unsigned short* __restrict__ BmT_all,
    const float* __restrict__ bias_all,
    const float* __restrict__ w0p, const float* __restrict__ w1p,
    const float* __restrict__ w2p, const float* __restrict__ w3p,
    float* __restrict__ m0, float* __restrict__ m1,
    float* __restrict__ m2, float* __restrict__ m3,
    unsigned short* __restrict__ xtm0)
{
    __shared__ unsigned short As[16384];     // [kk-chunk][row*32 + (i&31)]

    const int bid = blockIdx.x, tid = threadIdx.x;
    const float *x, *w; float* outp; unsigned short* xtm = nullptr;
    int set, mb, Lmask;
    if (bid < 256)       { x = xa; w = w0p; outp = m0; set = 0; mb = bid << 5;          Lmask = 63;  xtm = xtm0; }
    else if (bid < 768)  { x = xb; w = w1p; outp = m1; set = 1; mb = (bid - 256) << 5;  Lmask = 127; }
    else if (bid < 1792) { x = xc; w = w2p; outp = m2; set = 2; mb = (bid - 768) << 5;  Lmask = 255; }
    else                 { x = xd; w = w3p; outp = m3; set = 3; mb = (bid - 1792) << 5; Lmask = 511; }
    const int deg1m1 = set + 1;
    const int NK = deg1m1 << 2;
    const unsigned short* Bm = BmT_all + (size_t)set * 65536;
    const float* bias = bias_all + (set << 7);

    // ---- fused prep: u = tanh(tanh(x)); bf16 T-planes into As ----
    for (int e = tid * 4; e < 4096; e += 1024) {
        const int row = e >> 7, i = e & 127;
        float4 v = *(const float4*)(x + ((size_t)(mb + row)) * 128 + i);
        float u0 = fast_tanh(fast_tanh(v.x)), u1 = fast_tanh(fast_tanh(v.y));
        float u2 = fast_tanh(fast_tanh(v.z)), u3 = fast_tanh(fast_tanh(v.w));
        float tp0 = 1.f, tp1 = 1.f, tp2 = 1.f, tp3 = 1.f;
        float tc0 = u0, tc1 = u1, tc2 = u2, tc3 = u3;
        unsigned short* ap0 = &As[((i >> 5) << 10) + (row << 5) + (i & 31)];
        for (int p = 0; p < deg1m1; ++p) {
            unsigned short* ap = ap0 + (p << 12);
            ap[0] = f2bf(tc0); ap[1] = f2bf(tc1);
            ap[2] = f2bf(tc2); ap[3] = f2bf(tc3);
            float tn0 = fmaf(2.f * u0, tc0, -tp0); tp0 = tc0; tc0 = tn0;
            float tn1 = fmaf(2.f * u1, tc1, -tp1); tp1 = tc1; tc1 = tn1;
            float tn2 = fmaf(2.f * u2, tc2, -tp2); tp2 = tc2; tc2 = tn2;
            float tn3 = fmaf(2.f * u3, tc3, -tp3); tp3 = tc3; tc3 = tn3;
        }
    }

    const int ln = tid & 63, wv = tid >> 6;
    const int wm = wv & 1, wn = wv >> 1;
    const int lr = ln & 15, qd = ln >> 4;

    f32x4 acc[4];
    #pragma unroll
    for (int nt = 0; nt < 4; ++nt) acc[nt] = (f32x4){0.f, 0.f, 0.f, 0.f};

    // B fragment base (col fixed per thread); per-nt stride = 16 rows = 2048
    // shorts; per-kk offset = (kk>>2)*16384 + (kk&3)*32 shorts.
    const unsigned short* Bp = Bm + (((wn << 6) + lr) << 7) + (qd << 3);
    const unsigned short* Asp = &As[(((wm << 4) + lr) << 5) + (qd << 3)];

    bf16x8 bc[4], bn[4];
    #pragma unroll
    for (int nt = 0; nt < 4; ++nt)
        bc[nt] = *(const bf16x8*)(Bp + (nt << 11));        // kk=0 offset 0

    __syncthreads();                                       // As ready

    for (int kk = 0; kk < NK; ++kk) {
        const bool pf = (kk + 1 < NK);
        if (pf) {
            const int off = (((kk + 1) >> 2) << 14) + (((kk + 1) & 3) << 5);
            #pragma unroll
            for (int nt = 0; nt < 4; ++nt)
                bn[nt] = *(const bf16x8*)(Bp + (nt << 11) + off);
        }
        bf16x8 af = *(const bf16x8*)(Asp + (kk << 10));
        #pragma unroll
        for (int nt = 0; nt < 4; ++nt)
            acc[nt] = __builtin_amdgcn_mfma_f32_16x16x32_bf16(af, bc[nt], acc[nt], 0, 0, 0);
        if (pf) {
            #pragma unroll
            for (int nt = 0; nt < 4; ++nt) bc[nt] = bn[nt];
        }
    }

    // epilogue: bias + depthwise conv3 (+ optional bf16-T copy for level 0)
    #pragma unroll
    for (int nt = 0; nt < 4; ++nt) {
        const int col = (wn << 6) + (nt << 4) + lr;
        const float ww0 = w[col * 3 + 0], ww1 = w[col * 3 + 1], ww2 = w[col * 3 + 2];
        const float bs = bias[col];
        #pragma unroll
        for (int r = 0; r < 4; ++r) {
            const int row = (wm << 4) + (qd << 2) + r;
            const int gm = mb + row;
            const int n = gm & Lmask;
            const size_t gi = (size_t)gm * 128 + col;
            float xm1 = (n > 0)     ? x[gi - 128] : 0.f;
            float x0v = x[gi];
            float xp1 = (n < Lmask) ? x[gi + 128] : 0.f;
            float v = acc[nt][r] + bs + fmaf(ww0, xm1, fmaf(ww1, x0v, ww2 * xp1));
            outp[gi] = v;
            if (xtm)
                xtm[(size_t)(((gm >> 6) << 7) + col) * 64 + (gm & 63)] = f2bf(v);
        }
    }
}

// ---------------------------------------------------------------------------
extern "C" void kernel_launch(void* const* d_in, const int* in_sizes, int n_in,
                              void* d_out, int out_size, void* d_ws, size_t ws_size,
                              hipStream_t stream) {
    const float* x0 = (const float*)d_in[0];
    const float* x1 = (const float*)d_in[1];
    const float* x2 = (const float*)d_in[2];
    const float* x3 = (const float*)d_in[3];
    const float* c0 = (const float*)d_in[4];
    const float* w0 = (const float*)d_in[5];
    const float* c1 = (const float*)d_in[6];
    const float* w1 = (const float*)d_in[7];
    const float* c2 = (const float*)d_in[8];
    const float* w2 = (const float*)d_in[9];
    const float* c3 = (const float*)d_in[10];
    const float* w3 = (const float*)d_in[11];
    float* out = (float*)d_out;

    // ws: d0|d1|d2 (56MB) + Xt1..3 + Xtm0..2 (29MB) + BmT + bias + U (~0.9MB)
    float* d0 = (float*)d_ws;                               // 8388608 f
    float* d1 = d0 + 8388608;                               // 4194304 f
    float* d2 = d1 + 4194304;                               // 2097152 f
    unsigned short* Xt1  = (unsigned short*)(d2 + 2097152); // 4194304 us
    unsigned short* Xt2  = Xt1 + 4194304;                   // 2097152
    unsigned short* Xt3  = Xt2 + 2097152;                   // 1048576
    unsigned short* Xtm0 = Xt3 + 1048576;                   // 1048576
    unsigned short* Xtm1 = Xtm0 + 1048576;                  // 2097152
    unsigned short* Xtm2 = Xtm1 + 2097152;                  // 4194304
    unsigned short* BmT  = Xtm2 + 4194304;                  // 262144
    float* bias_all = (float*)(BmT + 262144);               // 512 f
    unsigned short* U256 = (unsigned short*)(bias_all + 512);
    unsigned short* U128 = U256 + 131072;
    unsigned short* U64p = U128 + 32768;                    // 8192

    float* m3 = out;                                        // (128,512,128)
    float* m2 = m3 + 8388608;                               // (128,256,128)
    float* m1 = m2 + 4194304;                               // (128,128,128)
    float* m0 = m1 + 2097152;                               // (128, 64,128)

    // 6 dispatches total
    prep_all<<<1824, 256, 0, stream>>>(x1, x2, x3, Xt1, Xt2, Xt3,
                                       U256, U128, U64p,
                                       c0, c1, c2, c3, BmT, bias_all);

    up2_dec<<<1792, 256, 0, stream>>>(U64p, U128, U256, Xt3, Xt2, Xt1,
                                      x2, x1, x0, d2, d1, d0);

    mkan_all<<<3840, 256, 0, stream>>>(x3, d2, d1, d0, BmT, bias_all,
                                       w0, w1, w2, w3, m0, m1, m2, m3, Xtm0);

    up2_mix<<<256,  256, 0, stream>>>(U64p, Xtm0, m1, Xtm1, 64, 1);
    up2_mix<<<512,  256, 0, stream>>>(U128, Xtm1, m2, Xtm2, 128, 2);
    up2_mix<<<1024, 256, 0, stream>>>(U256, Xtm2, m3, nullptr, 256, 3);
}

// Round 2
// 276.108 us; speedup vs baseline: 1.2511x; 1.2511x over previous
//
#include <hip/hip_runtime.h>
#include <math.h>

#define B_SZ 128
#define D_SZ 128

typedef __attribute__((ext_vector_type(8))) short bf16x8;
typedef __attribute__((ext_vector_type(4))) float f32x4;

__device__ __forceinline__ unsigned short f2bf(float f) {
    unsigned u = __float_as_uint(f);
    unsigned r = (u + 0x7FFF + ((u >> 16) & 1)) >> 16;   // RNE; inputs finite
    return (unsigned short)r;
}

// fast tanh: 1 - 2/(e^{2x}+1) via v_exp_f32 + v_rcp_f32 (~1e-6 abs err,
// well under bf16 truncation applied right after; absmax-validated in R5).
__device__ __forceinline__ float fast_tanh(float x) {
    float e2 = __builtin_amdgcn_exp2f(x * 2.885390081777927f);  // 2*log2(e)
    return fmaf(-2.0f, __builtin_amdgcn_rcpf(e2 + 1.0f), 1.0f);
}

// async global->LDS, 16B per lane. LDS dest must be wave-uniform base +
// lane*16 (hardware semantics, m104); all call sites below satisfy this.
__device__ __forceinline__ void gload_lds16(const unsigned short* g,
                                            unsigned short* l) {
    __builtin_amdgcn_global_load_lds(
        (const __attribute__((address_space(1))) unsigned int*)g,
        (__attribute__((address_space(3))) unsigned int*)l, 16, 0, 0);
}

// ---------------------------------------------------------------------------
// castT_tile: one 64(n) x 128(c) tile of fp32 (B,L,128) -> bf16 (B,128,L).
// ---------------------------------------------------------------------------
__device__ __forceinline__ void castT_tile(
    const float* __restrict__ src, unsigned short* __restrict__ dst,
    int b, int n0, int L)
{
    __shared__ unsigned short tt[128][72];
    const int tid = threadIdx.x;
    for (int i = tid; i < 64 * 32; i += 256) {
        int nr = i >> 5, c4 = (i & 31) * 4;
        float4 v = *(const float4*)(src + ((size_t)b * L + n0 + nr) * 128 + c4);
        tt[c4 + 0][nr] = f2bf(v.x);
        tt[c4 + 1][nr] = f2bf(v.y);
        tt[c4 + 2][nr] = f2bf(v.z);
        tt[c4 + 3][nr] = f2bf(v.w);
    }
    __syncthreads();
    const int c = tid >> 1, seg = (tid & 1) * 32;
    unsigned short* dp = dst + ((size_t)b * 128 + c) * L + n0 + seg;
    #pragma unroll
    for (int j = 0; j < 32; j += 8)
        *(bf16x8*)(dp + j) = *(const bf16x8*)&tt[c][seg + j];
}

// ---------------------------------------------------------------------------
// prep_all: ONE dispatch for all independent prep work.
// ---------------------------------------------------------------------------
__global__ __launch_bounds__(256) void prep_all(
    const float* __restrict__ x1, const float* __restrict__ x2,
    const float* __restrict__ x3,
    unsigned short* __restrict__ Xt1, unsigned short* __restrict__ Xt2,
    unsigned short* __restrict__ Xt3,
    unsigned short* __restrict__ U256, unsigned short* __restrict__ U128,
    unsigned short* __restrict__ U64p,
    const float* __restrict__ c0, const float* __restrict__ c1,
    const float* __restrict__ c2, const float* __restrict__ c3,
    unsigned short* __restrict__ BmT_all, float* __restrict__ bias_all)
{
    const int bid = blockIdx.x, tid = threadIdx.x;
    if (bid < 896) {
        if (bid < 512)      castT_tile(x1, Xt1, bid >> 2, (bid & 3) * 64, 256);
        else if (bid < 768) castT_tile(x2, Xt2, (bid - 512) >> 1, ((bid - 512) & 1) * 64, 128);
        else                castT_tile(x3, Xt3, bid - 768, 0, 64);
    } else if (bid < 1568) {
        // U[2t,n] = (t==n)*0.25 + (-1)^{t+n}/4L ; U[2t+1,n] = s((t-n)%L)/4L
        int fid = (bid - 896) * 256 + tid;
        unsigned short* U; int L, lg, e;
        if (fid < 131072)      { U = U256; L = 256; lg = 8; e = fid; }
        else if (fid < 163840) { U = U128; L = 128; lg = 7; e = fid - 131072; }
        else                   { U = U64p; L = 64;  lg = 6; e = fid - 163840; }
        const int n = e & (L - 1);
        const int m = e >> lg;
        const int t = m >> 1;
        const float inv4L = 1.0f / (4.0f * (float)L);
        float val;
        if ((m & 1) == 0) {
            val = ((t == n) ? 0.25f : 0.0f) + (((t + n) & 1) ? -inv4L : inv4L);
        } else {
            int idx = (t - n) & (L - 1);
            double th = M_PI * (2.0 * idx + 1.0) / (2.0 * L);
            double ct = cos(th) / sin(th);
            val = (float)((idx & 1) ? -ct : ct) * inv4L;
        }
        U[e] = f2bf(val);
    } else {
        // convb: BmT[set][d-1][o][i] = bf16(coeffs[i,o,d]); bias = sum_i c[i,o,0]
        const int r   = bid - 1568;          // 0..255
        const int set = r >> 6;              // 0..3  (DEG1 = set+2)
        const int o   = ((r & 63) << 1) + (tid >> 7);
        const int i   = tid & 127;
        const int DEG1 = set + 2;
        const float* cc = (set == 0) ? c0 : (set == 1) ? c1 : (set == 2) ? c2 : c3;
        const float* cp = cc + ((size_t)i * 128 + o) * DEG1;
        unsigned short* Bm = BmT_all + (size_t)set * 65536;
        for (int d = 1; d < DEG1; ++d)
            Bm[(size_t)(d - 1) * 16384 + o * 128 + i] = f2bf(cp[d]);
        float s = cp[0];
        #pragma unroll
        for (int off = 32; off >= 1; off >>= 1) s += __shfl_down(s, off);
        __shared__ float red[4];
        if ((tid & 63) == 0) red[tid >> 6] = s;
        __syncthreads();
        if ((tid & 127) == 0)
            bias_all[set * 128 + o] = red[tid >> 6] + red[(tid >> 6) + 1];
    }
}

// ---------------------------------------------------------------------------
// up2_body: out[b,m,c] = xh[b,m,c] + sign * sum_n U[m,n]*Xt[b,c,n]
// 64x128 tile, 4 waves 2x2 of 32x64, mfma 16x16x32 bf16, runtime L.
// R6: back to the R4 LDS double-buffered skeleton (R5's direct-global was
// L2-latency-bound), but staging now uses async global_load_lds dwordx4
// (no VGPR round-trip, no staging VALU). LDS dests are wave-uniform base
// + lane*16 as required.
// ---------------------------------------------------------------------------
__device__ __forceinline__ void up2_body(
    const unsigned short* __restrict__ U,
    const unsigned short* __restrict__ Xt,
    const float* __restrict__ xh,
    float* __restrict__ out,
    unsigned short* __restrict__ xtm,
    float sign, int b, int mt, int L)
{
    const int NK = L >> 5;
    const int tid = threadIdx.x;
    __shared__ unsigned short Ab[2][2048];
    __shared__ unsigned short Bb[2][4096];

    const int ln = tid & 63, wv = tid >> 6;
    const int wm = wv & 1, wn = wv >> 1;
    const int lr = ln & 15, qd = ln >> 4;

    f32x4 acc[2][4];
    #pragma unroll
    for (int mi = 0; mi < 2; ++mi)
        #pragma unroll
        for (int nt = 0; nt < 4; ++nt)
            acc[mi][nt] = (f32x4){0.f, 0.f, 0.f, 0.f};

    const int arow = tid >> 2, acol = (tid & 3) * 8;

    auto stage = [&](int kk, int buf) {
        const unsigned short* ga = U + (size_t)(mt * 64 + arow) * L + kk * 32 + acol;
        gload_lds16(ga, (unsigned short*)Ab[buf] + (tid << 3));
        #pragma unroll
        for (int j = 0; j < 2; ++j) {
            int sidx = tid + (j << 8);
            const unsigned short* gb =
                Xt + ((size_t)b * 128 + (sidx >> 2)) * L + kk * 32 + (sidx & 3) * 8;
            gload_lds16(gb, (unsigned short*)Bb[buf] + (sidx << 3));
        }
    };

    stage(0, 0);
    for (int kk = 0; kk < NK; ++kk) {
        __syncthreads();                     // drains the async loads for buf kk
        if (kk + 1 < NK) stage(kk + 1, (kk + 1) & 1);
        const int buf = kk & 1;
        bf16x8 af[2], bfv[4];
        #pragma unroll
        for (int mi = 0; mi < 2; ++mi)
            af[mi] = *(const bf16x8*)&Ab[buf][(wm * 32 + mi * 16 + lr) * 32 + qd * 8];
        #pragma unroll
        for (int nt = 0; nt < 4; ++nt)
            bfv[nt] = *(const bf16x8*)&Bb[buf][(wn * 64 + nt * 16 + lr) * 32 + qd * 8];
        #pragma unroll
        for (int mi = 0; mi < 2; ++mi)
            #pragma unroll
            for (int nt = 0; nt < 4; ++nt)
                acc[mi][nt] = __builtin_amdgcn_mfma_f32_16x16x32_bf16(
                    af[mi], bfv[nt], acc[mi][nt], 0, 0, 0);
    }

    const int twoL = L << 1;
    #pragma unroll
    for (int nt = 0; nt < 4; ++nt) {
        const int col = wn * 64 + nt * 16 + lr;
        #pragma unroll
        for (int mi = 0; mi < 2; ++mi) {
            #pragma unroll
            for (int r = 0; r < 4; ++r) {
                const int row = mt * 64 + wm * 32 + mi * 16 + qd * 4 + r;
                const size_t gi = ((size_t)b * twoL + row) * 128 + col;
                float v = xh[gi] + sign * acc[mi][nt][r];
                out[gi] = v;
                if (xtm)
                    xtm[((size_t)b * 128 + col) * twoL + row] = f2bf(v);
            }
        }
    }
}

// up2_dec: all three decomposition GEMMs in ONE dispatch.
__global__ __launch_bounds__(256) void up2_dec(
    const unsigned short* __restrict__ U64p, const unsigned short* __restrict__ U128,
    const unsigned short* __restrict__ U256,
    const unsigned short* __restrict__ Xt3, const unsigned short* __restrict__ Xt2,
    const unsigned short* __restrict__ Xt1,
    const float* __restrict__ x2, const float* __restrict__ x1,
    const float* __restrict__ x0,
    float* __restrict__ d2, float* __restrict__ d1, float* __restrict__ d0)
{
    const int bid = blockIdx.x;
    const unsigned short *U, *Xt; const float* xh; float* out;
    int L, lgMT, base;
    if (bid < 256)      { U = U64p; Xt = Xt3; xh = x2; out = d2; L = 64;  lgMT = 1; base = 0; }
    else if (bid < 768) { U = U128; Xt = Xt2; xh = x1; out = d1; L = 128; lgMT = 2; base = 256; }
    else                { U = U256; Xt = Xt1; xh = x0; out = d0; L = 256; lgMT = 3; base = 768; }
    const int rb = bid - base;
    up2_body(U, Xt, xh, out, nullptr, -1.f, rb >> lgMT, rb & ((1 << lgMT) - 1), L);
}

// up2_mix: one mix-chain up-add (in-place), optional Xtm emit for next level.
__global__ __launch_bounds__(256) void up2_mix(
    const unsigned short* __restrict__ U, const unsigned short* __restrict__ Xt,
    float* __restrict__ m, unsigned short* __restrict__ xtm, int L, int lgMT)
{
    up2_body(U, Xt, m, m, xtm, 1.f,
             blockIdx.x >> lgMT, blockIdx.x & ((1 << lgMT) - 1), L);
}

// ---------------------------------------------------------------------------
// mkan_all: ALL FOUR mkan levels in one dispatch, prep_T fused in-LDS.
// R6: R4's double-buffered Bb LDS staging restored (proven 87.6us; R5's
// direct-global was latency-bound), staging via global_load_lds dwordx4,
// prep tanh via fast exp2/rcp (validated in R5, absmax unchanged).
// LDS: As 32KB + Bb 16KB = 48KB -> 3 blocks/CU.
// ---------------------------------------------------------------------------
__global__ __launch_bounds__(256) void mkan_all(
    const float* __restrict__ xa, const float* __restrict__ xb,
    const float* __restrict__ xc, const float* __restrict__ xd,
    const unsigned short* __restrict__ BmT_all,
    const float* __restrict__ bias_all,
    const float* __restrict__ w0p, const float* __restrict__ w1p,
    const float* __restrict__ w2p, const float* __restrict__ w3p,
    float* __restrict__ m0, float* __restrict__ m1,
    float* __restrict__ m2, float* __restrict__ m3,
    unsigned short* __restrict__ xtm0)
{
    __shared__ unsigned short As[16384];     // [kk-chunk][row*32 + (i&31)]
    __shared__ unsigned short Bb[2][4096];

    const int bid = blockIdx.x, tid = threadIdx.x;
    const float *x, *w; float* outp; unsigned short* xtm = nullptr;
    int set, mb, Lmask;
    if (bid < 256)       { x = xa; w = w0p; outp = m0; set = 0; mb = bid << 5;          Lmask = 63;  xtm = xtm0; }
    else if (bid < 768)  { x = xb; w = w1p; outp = m1; set = 1; mb = (bid - 256) << 5;  Lmask = 127; }
    else if (bid < 1792) { x = xc; w = w2p; outp = m2; set = 2; mb = (bid - 768) << 5;  Lmask = 255; }
    else                 { x = xd; w = w3p; outp = m3; set = 3; mb = (bid - 1792) << 5; Lmask = 511; }
    const int deg1m1 = set + 1;
    const int NK = deg1m1 << 2;
    const unsigned short* Bm = BmT_all + (size_t)set * 65536;
    const float* bias = bias_all + (set << 7);

    // ---- fused prep: u = tanh(tanh(x)); bf16 T-planes into As ----
    for (int e = tid * 4; e < 4096; e += 1024) {
        const int row = e >> 7, i = e & 127;
        float4 v = *(const float4*)(x + ((size_t)(mb + row)) * 128 + i);
        float u0 = fast_tanh(fast_tanh(v.x)), u1 = fast_tanh(fast_tanh(v.y));
        float u2 = fast_tanh(fast_tanh(v.z)), u3 = fast_tanh(fast_tanh(v.w));
        float tp0 = 1.f, tp1 = 1.f, tp2 = 1.f, tp3 = 1.f;
        float tc0 = u0, tc1 = u1, tc2 = u2, tc3 = u3;
        unsigned short* ap0 = &As[((i >> 5) << 10) + (row << 5) + (i & 31)];
        for (int p = 0; p < deg1m1; ++p) {
            unsigned short* ap = ap0 + (p << 12);
            ap[0] = f2bf(tc0); ap[1] = f2bf(tc1);
            ap[2] = f2bf(tc2); ap[3] = f2bf(tc3);
            float tn0 = fmaf(2.f * u0, tc0, -tp0); tp0 = tc0; tc0 = tn0;
            float tn1 = fmaf(2.f * u1, tc1, -tp1); tp1 = tc1; tc1 = tn1;
            float tn2 = fmaf(2.f * u2, tc2, -tp2); tp2 = tc2; tc2 = tn2;
            float tn3 = fmaf(2.f * u3, tc3, -tp3); tp3 = tc3; tc3 = tn3;
        }
    }

    const int ln = tid & 63, wv = tid >> 6;
    const int wm = wv & 1, wn = wv >> 1;
    const int lr = ln & 15, qd = ln >> 4;

    f32x4 acc[4];
    #pragma unroll
    for (int nt = 0; nt < 4; ++nt) acc[nt] = (f32x4){0.f, 0.f, 0.f, 0.f};

    auto stageB = [&](int kk, int buf) {
        const int p = kk >> 2, i0 = (kk & 3) << 5;
        #pragma unroll
        for (int j = 0; j < 2; ++j) {
            int sidx = tid + (j << 8);
            const unsigned short* gb =
                Bm + (size_t)((p << 7) + (sidx >> 2)) * 128 + i0 + ((sidx & 3) << 3);
            gload_lds16(gb, (unsigned short*)Bb[buf] + (sidx << 3));
        }
    };

    stageB(0, 0);
    for (int kk = 0; kk < NK; ++kk) {
        __syncthreads();                     // covers As prep (kk=0) + Bb[buf]
        if (kk + 1 < NK) stageB(kk + 1, (kk + 1) & 1);
        const int buf = kk & 1;
        bf16x8 af = *(const bf16x8*)&As[(kk << 10) + (((wm << 4) + lr) << 5) + (qd << 3)];
        bf16x8 bfv[4];
        #pragma unroll
        for (int nt = 0; nt < 4; ++nt)
            bfv[nt] = *(const bf16x8*)&Bb[buf][(((wn << 6) + (nt << 4) + lr) << 5) + (qd << 3)];
        #pragma unroll
        for (int nt = 0; nt < 4; ++nt)
            acc[nt] = __builtin_amdgcn_mfma_f32_16x16x32_bf16(af, bfv[nt], acc[nt], 0, 0, 0);
    }

    // epilogue: bias + depthwise conv3 (+ optional bf16-T copy for level 0)
    #pragma unroll
    for (int nt = 0; nt < 4; ++nt) {
        const int col = (wn << 6) + (nt << 4) + lr;
        const float ww0 = w[col * 3 + 0], ww1 = w[col * 3 + 1], ww2 = w[col * 3 + 2];
        const float bs = bias[col];
        #pragma unroll
        for (int r = 0; r < 4; ++r) {
            const int row = (wm << 4) + (qd << 2) + r;
            const int gm = mb + row;
            const int n = gm & Lmask;
            const size_t gi = (size_t)gm * 128 + col;
            float xm1 = (n > 0)     ? x[gi - 128] : 0.f;
            float x0v = x[gi];
            float xp1 = (n < Lmask) ? x[gi + 128] : 0.f;
            float v = acc[nt][r] + bs + fmaf(ww0, xm1, fmaf(ww1, x0v, ww2 * xp1));
            outp[gi] = v;
            if (xtm)
                xtm[(size_t)(((gm >> 6) << 7) + col) * 64 + (gm & 63)] = f2bf(v);
        }
    }
}

// ---------------------------------------------------------------------------
extern "C" void kernel_launch(void* const* d_in, const int* in_sizes, int n_in,
                              void* d_out, int out_size, void* d_ws, size_t ws_size,
                              hipStream_t stream) {
    const float* x0 = (const float*)d_in[0];
    const float* x1 = (const float*)d_in[1];
    const float* x2 = (const float*)d_in[2];
    const float* x3 = (const float*)d_in[3];
    const float* c0 = (const float*)d_in[4];
    const float* w0 = (const float*)d_in[5];
    const float* c1 = (const float*)d_in[6];
    const float* w1 = (const float*)d_in[7];
    const float* c2 = (const float*)d_in[8];
    const float* w2 = (const float*)d_in[9];
    const float* c3 = (const float*)d_in[10];
    const float* w3 = (const float*)d_in[11];
    float* out = (float*)d_out;

    // ws: d0|d1|d2 (56MB) + Xt1..3 + Xtm0..2 (29MB) + BmT + bias + U (~0.9MB)
    float* d0 = (float*)d_ws;                               // 8388608 f
    float* d1 = d0 + 8388608;                               // 4194304 f
    float* d2 = d1 + 4194304;                               // 2097152 f
    unsigned short* Xt1  = (unsigned short*)(d2 + 2097152); // 4194304 us
    unsigned short* Xt2  = Xt1 + 4194304;                   // 2097152
    unsigned short* Xt3  = Xt2 + 2097152;                   // 1048576
    unsigned short* Xtm0 = Xt3 + 1048576;                   // 1048576
    unsigned short* Xtm1 = Xtm0 + 1048576;                  // 2097152
    unsigned short* Xtm2 = Xtm1 + 2097152;                  // 4194304
    unsigned short* BmT  = Xtm2 + 4194304;                  // 262144
    float* bias_all = (float*)(BmT + 262144);               // 512 f
    unsigned short* U256 = (unsigned short*)(bias_all + 512);
    unsigned short* U128 = U256 + 131072;
    unsigned short* U64p = U128 + 32768;                    // 8192

    float* m3 = out;                                        // (128,512,128)
    float* m2 = m3 + 8388608;                               // (128,256,128)
    float* m1 = m2 + 4194304;                               // (128,128,128)
    float* m0 = m1 + 2097152;                               // (128, 64,128)

    // 6 dispatches total
    prep_all<<<1824, 256, 0, stream>>>(x1, x2, x3, Xt1, Xt2, Xt3,
                                       U256, U128, U64p,
                                       c0, c1, c2, c3, BmT, bias_all);

    up2_dec<<<1792, 256, 0, stream>>>(U64p, U128, U256, Xt3, Xt2, Xt1,
                                      x2, x1, x0, d2, d1, d0);

    mkan_all<<<3840, 256, 0, stream>>>(x3, d2, d1, d0, BmT, bias_all,
                                       w0, w1, w2, w3, m0, m1, m2, m3, Xtm0);

    up2_mix<<<256,  256, 0, stream>>>(U64p, Xtm0, m1, Xtm1, 64, 1);
    up2_mix<<<512,  256, 0, stream>>>(U128, Xtm1, m2, Xtm2, 128, 2);
    up2_mix<<<1024, 256, 0, stream>>>(U256, Xtm2, m3, nullptr, 256, 3);
}